// Round 2
// baseline (375.609 us; speedup 1.0000x reference)
//
#include <hip/hip_runtime.h>
#include <hip/hip_bf16.h>

#define NN 10000
#define NE 320000
#define IND 512
#define HD 256
#define NH 8
#define DH 32
#define OD 40
#define NEG 0.2f

// ---- dtype detection: flag=1 if float buffers are bf16, 0 if fp32 ----------
__global__ void k_detect(const unsigned short* __restrict__ w, int* __restrict__ flag){
    if (threadIdx.x == 0 && blockIdx.x == 0){
        int cnt = 0;
        for (int i = 0; i < 256; i++){
            unsigned int u = ((unsigned int)w[i]) << 16;
            float v = __uint_as_float(u);
            float av = fabsf(v);
            if (!(av < 0.5f)) cnt++;   // catches big values, Inf, NaN
        }
        *flag = (cnt < 8) ? 1 : 0;     // few hits -> genuine bf16
    }
}

__global__ void k_zero_i(int* __restrict__ p, int n){
    int i = blockIdx.x*blockDim.x + threadIdx.x;
    if (i < n) p[i] = 0;
}

// ---- dtype-flexible convert-to-fp32 ----------------------------------------
__global__ void cvt_any(const void* __restrict__ in, float* __restrict__ out, int n,
                        const int* __restrict__ flag){
    int i = blockIdx.x*blockDim.x + threadIdx.x;
    if (i >= n) return;
    if (*flag) out[i] = __bfloat162float(((const __hip_bfloat16*)in)[i]);
    else       out[i] = ((const float*)in)[i];
}

// ---- dtype-flexible store --------------------------------------------------
__global__ void store_any(const float* __restrict__ in, void* __restrict__ out, int n,
                          const int* __restrict__ flag){
    int i = blockIdx.x*blockDim.x + threadIdx.x;
    if (i >= n) return;
    if (*flag) ((__hip_bfloat16*)out)[i] = __float2bfloat16(in[i]);
    else       ((float*)out)[i] = in[i];
}

// ---- CSR build -------------------------------------------------------------
__global__ void k_hist(const int* __restrict__ dst, int* __restrict__ deg){
    int e = blockIdx.x*blockDim.x + threadIdx.x;
    if (e < NE) atomicAdd(&deg[dst[e]], 1);
}

__global__ void k_scan(const int* __restrict__ deg, int* __restrict__ rowptr, int* __restrict__ cnt){
    __shared__ int sums[1024];
    int t = threadIdx.x;
    int base = t * 10;
    int local[10];
    int s = 0;
    #pragma unroll
    for (int i = 0; i < 10; i++){
        int idx = base + i;
        int v = (idx < NN) ? deg[idx] : 0;
        local[i] = s; s += v;
    }
    sums[t] = s;
    __syncthreads();
    for (int off = 1; off < 1024; off <<= 1){
        int v = (t >= off) ? sums[t - off] : 0;
        __syncthreads();
        sums[t] += v;
        __syncthreads();
    }
    int excl = sums[t] - s;
    #pragma unroll
    for (int i = 0; i < 10; i++){
        int idx = base + i;
        if (idx < NN){ int v = excl + local[i]; rowptr[idx] = v; cnt[idx] = v; }
    }
    if (t == 1023) rowptr[NN] = sums[1023];
}

__global__ void k_fill(const int* __restrict__ src, const int* __restrict__ dst,
                       int* __restrict__ cnt, int* __restrict__ col){
    int e = blockIdx.x*blockDim.x + threadIdx.x;
    if (e < NE){
        int p = atomicAdd(&cnt[dst[e]], 1);
        col[p] = src[e];
    }
}

// ---- fp32 GEMM: C[M,N] = A[M,K] @ B[K,N] (+bias). 64x64 tile, 4x4/thread ---
__global__ __launch_bounds__(256)
void k_gemm(const float* __restrict__ A, const float* __restrict__ B,
            const float* __restrict__ bias, float* __restrict__ C,
            int M, int N, int K){
    __shared__ float As[16][68];
    __shared__ float Bs[16][68];
    int t = threadIdx.x;
    int tx = t & 15, ty = t >> 4;
    int rowBase = blockIdx.x * 64;
    int colBase = blockIdx.y * 64;
    int am = t >> 2;
    int ak = (t & 3) << 2;
    int bk = t >> 4;
    int bn = (t & 15) << 2;
    float acc[4][4] = {{0.f}};
    int arow = rowBase + am; if (arow > M - 1) arow = M - 1;
    const float* Aptr = A + (size_t)arow * K + ak;
    for (int k0 = 0; k0 < K; k0 += 16){
        float4 av = *(const float4*)(Aptr + k0);
        int bcol = colBase + bn;
        const float* Brow = B + (size_t)(k0 + bk) * N;
        float4 bv;
        if (bcol + 3 < N){
            bv = *(const float4*)(Brow + bcol);
        } else {
            bv.x = (bcol + 0 < N) ? Brow[bcol + 0] : 0.f;
            bv.y = (bcol + 1 < N) ? Brow[bcol + 1] : 0.f;
            bv.z = (bcol + 2 < N) ? Brow[bcol + 2] : 0.f;
            bv.w = (bcol + 3 < N) ? Brow[bcol + 3] : 0.f;
        }
        As[ak + 0][am] = av.x; As[ak + 1][am] = av.y;
        As[ak + 2][am] = av.z; As[ak + 3][am] = av.w;
        *(float4*)&Bs[bk][bn] = bv;
        __syncthreads();
        #pragma unroll
        for (int kk = 0; kk < 16; kk++){
            float4 a4 = *(const float4*)&As[kk][ty << 2];
            float4 b4 = *(const float4*)&Bs[kk][tx << 2];
            float aa[4] = {a4.x, a4.y, a4.z, a4.w};
            float bb[4] = {b4.x, b4.y, b4.z, b4.w};
            #pragma unroll
            for (int i = 0; i < 4; i++)
                #pragma unroll
                for (int j = 0; j < 4; j++)
                    acc[i][j] += aa[i] * bb[j];
        }
        __syncthreads();
    }
    #pragma unroll
    for (int i = 0; i < 4; i++){
        int row = rowBase + (ty << 2) + i;
        if (row < M){
            #pragma unroll
            for (int j = 0; j < 4; j++){
                int colv = colBase + (tx << 2) + j;
                if (colv < N){
                    float v = acc[i][j] + (bias ? bias[colv] : 0.f);
                    C[(size_t)row * N + colv] = v;
                }
            }
        }
    }
}

// ---- attention logits: one wave per node -----------------------------------
__global__ __launch_bounds__(256)
void k_alpha(const float* __restrict__ Wh, const float* __restrict__ asrc,
             const float* __restrict__ adst, float* __restrict__ als, float* __restrict__ ald){
    int node = blockIdx.x * 4 + (threadIdx.x >> 6);
    int lane = threadIdx.x & 63;
    if (node >= NN) return;
    float4 w  = *(const float4*)&Wh[(size_t)node * HD + (lane << 2)];
    float4 s4 = *(const float4*)&asrc[lane << 2];
    float4 d4 = *(const float4*)&adst[lane << 2];
    float ps = w.x*s4.x + w.y*s4.y + w.z*s4.z + w.w*s4.w;
    float pd = w.x*d4.x + w.y*d4.y + w.z*d4.z + w.w*d4.w;
    ps += __shfl_xor(ps, 1); pd += __shfl_xor(pd, 1);
    ps += __shfl_xor(ps, 2); pd += __shfl_xor(pd, 2);
    ps += __shfl_xor(ps, 4); pd += __shfl_xor(pd, 4);
    if ((lane & 7) == 0){
        als[node * NH + (lane >> 3)] = ps;
        ald[node * NH + (lane >> 3)] = pd;
    }
}

// ---- per-destination softmax + aggregation (one wave per node) -------------
__global__ __launch_bounds__(64)
void k_agg(const int* __restrict__ rowptr, const int* __restrict__ col,
           const float* __restrict__ Wh, const float* __restrict__ als,
           const float* __restrict__ ald, float* __restrict__ out){
    __shared__ float pshm[64][NH];
    __shared__ int scol[64];
    int node = blockIdx.x;
    int lane = threadIdx.x;
    int b = rowptr[node], e = rowptr[node + 1];
    int hL = lane >> 3;
    float ad[NH];
    #pragma unroll
    for (int h = 0; h < NH; h++) ad[h] = ald[node * NH + h];
    float m[NH], den[NH];
    #pragma unroll
    for (int h = 0; h < NH; h++){ m[h] = -INFINITY; den[h] = 0.f; }
    float4 acc = make_float4(0.f, 0.f, 0.f, 0.f);

    for (int cb = b; cb < e; cb += 64){
        int ne_ = min(64, e - cb);
        float ev[NH];
        if (lane < ne_){
            int s = col[cb + lane];
            scol[lane] = s;
            const float* ap = &als[(size_t)s * NH];
            #pragma unroll
            for (int h = 0; h < NH; h++){
                float v = ap[h] + ad[h];
                ev[h] = v > 0.f ? v : NEG * v;
            }
        } else {
            #pragma unroll
            for (int h = 0; h < NH; h++) ev[h] = -INFINITY;
        }
        float cm[NH];
        #pragma unroll
        for (int h = 0; h < NH; h++) cm[h] = ev[h];
        #pragma unroll
        for (int off = 1; off < 64; off <<= 1){
            #pragma unroll
            for (int h = 0; h < NH; h++) cm[h] = fmaxf(cm[h], __shfl_xor(cm[h], off));
        }
        float r[NH];
        #pragma unroll
        for (int h = 0; h < NH; h++){
            float nm = fmaxf(m[h], cm[h]);
            r[h] = __expf(m[h] - nm);
            den[h] *= r[h];
            m[h] = nm;
        }
        float rr = r[hL];
        acc.x *= rr; acc.y *= rr; acc.z *= rr; acc.w *= rr;
        float dp[NH];
        if (lane < ne_){
            #pragma unroll
            for (int h = 0; h < NH; h++){
                float p = __expf(ev[h] - m[h]);
                pshm[lane][h] = p;
                dp[h] = p;
            }
        } else {
            #pragma unroll
            for (int h = 0; h < NH; h++) dp[h] = 0.f;
        }
        #pragma unroll
        for (int off = 1; off < 64; off <<= 1){
            #pragma unroll
            for (int h = 0; h < NH; h++) dp[h] += __shfl_xor(dp[h], off);
        }
        #pragma unroll
        for (int h = 0; h < NH; h++) den[h] += dp[h];
        __syncthreads();
        for (int j = 0; j < ne_; j++){
            int s = scol[j];
            float p = pshm[j][hL];
            float4 w = *(const float4*)&Wh[(size_t)s * HD + (lane << 2)];
            acc.x += p * w.x; acc.y += p * w.y; acc.z += p * w.z; acc.w += p * w.w;
        }
        __syncthreads();
    }
    float dn = fmaxf(den[hL], 1e-9f);
    float inv = 1.f / dn;
    acc.x *= inv; acc.y *= inv; acc.z *= inv; acc.w *= inv;
    acc.x = fmaxf(acc.x, 0.f); acc.y = fmaxf(acc.y, 0.f);
    acc.z = fmaxf(acc.z, 0.f); acc.w = fmaxf(acc.w, 0.f);
    *(float4*)&out[(size_t)node * HD + (lane << 2)] = acc;
}

extern "C" void kernel_launch(void* const* d_in, const int* in_sizes, int n_in,
                              void* d_out, int out_size, void* d_ws, size_t ws_size,
                              hipStream_t stream){
    const void* x_p   = d_in[0];
    const int*  eidx  = (const int*)d_in[1];
    const void* Win_p = d_in[2];
    const void* bin_p = d_in[3];
    const void* W1_p  = d_in[4];
    const void* a1s_p = d_in[5];
    const void* a1d_p = d_in[6];
    const void* W2_p  = d_in[7];
    const void* a2s_p = d_in[8];
    const void* a2d_p = d_in[9];
    const void* Wo_p  = d_in[10];
    const void* bo_p  = d_in[11];

    float* ws = (float*)d_ws;
    size_t off = 0;
    auto alloc = [&](size_t n){ float* p = ws + off; off += n; return p; };
    float* xf   = alloc((size_t)NN * IND);        // also reused for outf
    float* Winf = alloc((size_t)IND * HD);
    float* binf = alloc(HD);
    float* W1f  = alloc(HD * HD);
    float* a1sf = alloc(HD);
    float* a1df = alloc(HD);
    float* W2f  = alloc(HD * HD);
    float* a2sf = alloc(HD);
    float* a2df = alloc(HD);
    float* Wof  = alloc(HD * OD);
    float* bof  = alloc(64);
    float* h1   = alloc((size_t)NN * HD);         // also reused for h3
    float* Wh   = alloc((size_t)NN * HD);
    float* h2   = alloc((size_t)NN * HD);
    float* als  = alloc((size_t)NN * NH);
    float* ald  = alloc((size_t)NN * NH);
    int* rowptr = (int*)(ws + off); off += NN + 1;
    int* cnt    = (int*)(ws + off); off += NN;
    int* deg    = (int*)(ws + off); off += NN;
    int* col    = (int*)(ws + off); off += NE;
    int* dflag  = (int*)(ws + off); off += 4;
    float* h3   = h1;
    float* outf = xf;

    const int* src = eidx;
    const int* dst = eidx + NE;

    auto cdiv = [](int a, int b){ return (a + b - 1) / b; };

    // dtype detection on W_in
    k_detect<<<1,64,0,stream>>>((const unsigned short*)Win_p, dflag);

    // convert inputs to fp32 scratch
    cvt_any<<<cdiv(NN*IND,256),256,0,stream>>>(x_p, xf, NN*IND, dflag);
    cvt_any<<<cdiv(IND*HD,256),256,0,stream>>>(Win_p, Winf, IND*HD, dflag);
    cvt_any<<<1,256,0,stream>>>(bin_p, binf, HD, dflag);
    cvt_any<<<cdiv(HD*HD,256),256,0,stream>>>(W1_p, W1f, HD*HD, dflag);
    cvt_any<<<1,256,0,stream>>>(a1s_p, a1sf, HD, dflag);
    cvt_any<<<1,256,0,stream>>>(a1d_p, a1df, HD, dflag);
    cvt_any<<<cdiv(HD*HD,256),256,0,stream>>>(W2_p, W2f, HD*HD, dflag);
    cvt_any<<<1,256,0,stream>>>(a2s_p, a2sf, HD, dflag);
    cvt_any<<<1,256,0,stream>>>(a2d_p, a2df, HD, dflag);
    cvt_any<<<cdiv(HD*OD,256),256,0,stream>>>(Wo_p, Wof, HD*OD, dflag);
    cvt_any<<<1,64,0,stream>>>(bo_p, bof, OD, dflag);

    // CSR by destination (shared by both layers)
    k_zero_i<<<cdiv(NN,256),256,0,stream>>>(deg, NN);
    k_hist<<<cdiv(NE,256),256,0,stream>>>(dst, deg);
    k_scan<<<1,1024,0,stream>>>(deg, rowptr, cnt);
    k_fill<<<cdiv(NE,256),256,0,stream>>>(src, dst, cnt, col);

    // input linear
    k_gemm<<<dim3(cdiv(NN,64), cdiv(HD,64)),256,0,stream>>>(xf, Winf, binf, h1, NN, HD, IND);

    // GAT layer 1
    k_gemm<<<dim3(cdiv(NN,64), cdiv(HD,64)),256,0,stream>>>(h1, W1f, nullptr, Wh, NN, HD, HD);
    k_alpha<<<cdiv(NN,4),256,0,stream>>>(Wh, a1sf, a1df, als, ald);
    k_agg<<<NN,64,0,stream>>>(rowptr, col, Wh, als, ald, h2);

    // GAT layer 2
    k_gemm<<<dim3(cdiv(NN,64), cdiv(HD,64)),256,0,stream>>>(h2, W2f, nullptr, Wh, NN, HD, HD);
    k_alpha<<<cdiv(NN,4),256,0,stream>>>(Wh, a2sf, a2df, als, ald);
    k_agg<<<NN,64,0,stream>>>(rowptr, col, Wh, als, ald, h3);

    // output head
    k_gemm<<<dim3(cdiv(NN,64), cdiv(OD,64)),256,0,stream>>>(h3, Wof, bof, outf, NN, OD, HD);
    store_any<<<cdiv(NN*OD,256),256,0,stream>>>(outf, d_out, NN*OD, dflag);
}

// Round 3
// 266.171 us; speedup vs baseline: 1.4112x; 1.4112x over previous
//
#include <hip/hip_runtime.h>
#include <hip/hip_bf16.h>

#define NN 10000
#define NE 320000
#define IND 512
#define HD 256
#define NH 8
#define DH 32
#define OD 40
#define NEG 0.2f

typedef __attribute__((ext_vector_type(8))) short bf16x8;
typedef __attribute__((ext_vector_type(4))) float f32x4;

__device__ __forceinline__ float bf2f(unsigned short u){
    return __uint_as_float(((unsigned)u) << 16);
}
__device__ __forceinline__ unsigned short f2bf(float v){
    __hip_bfloat16 h = __float2bfloat16(v);
    return *(unsigned short*)&h;
}

// ---- dtype detection: flag=1 if float buffers are bf16, 0 if fp32 ----------
__global__ void k_detect(const unsigned short* __restrict__ w, int* __restrict__ flag){
    if (threadIdx.x == 0 && blockIdx.x == 0){
        int cnt = 0;
        for (int i = 0; i < 256; i++){
            float av = fabsf(bf2f(w[i]));
            if (!(av < 0.5f)) cnt++;   // big values / Inf / NaN -> fp32 bits
        }
        *flag = (cnt < 8) ? 1 : 0;
    }
}

__global__ void k_zero_i(int* __restrict__ p, int n){
    int i = blockIdx.x*blockDim.x + threadIdx.x;
    if (i < n) p[i] = 0;
}

// ---- x -> bf16 (vectorized, flag-aware) ------------------------------------
__global__ void k_prep_x(const void* __restrict__ in, unsigned short* __restrict__ out,
                         int n8, const int* __restrict__ flag){
    int i = blockIdx.x*blockDim.x + threadIdx.x;
    if (i >= n8) return;
    if (*flag){
        ((ushort4*)out)[i*2]   = ((const ushort4*)in)[i*2];
        ((ushort4*)out)[i*2+1] = ((const ushort4*)in)[i*2+1];
    } else {
        const float4* f = (const float4*)in;
        float4 a = f[i*2], b = f[i*2+1];
        ushort4 o0, o1;
        o0.x=f2bf(a.x); o0.y=f2bf(a.y); o0.z=f2bf(a.z); o0.w=f2bf(a.w);
        o1.x=f2bf(b.x); o1.y=f2bf(b.y); o1.z=f2bf(b.z); o1.w=f2bf(b.w);
        ((ushort4*)out)[i*2] = o0; ((ushort4*)out)[i*2+1] = o1;
    }
}

// ---- all small vectors -> fp32 in one launch --------------------------------
__global__ void k_cvt_small(const void* bin, const void* a1s, const void* a1d,
                            const void* a2s, const void* a2d, const void* bo,
                            float* binf, float* a1sf, float* a1df,
                            float* a2sf, float* a2df, float* bof,
                            const int* __restrict__ flag){
    int t = threadIdx.x;
    int f = *flag;
    #define CV(p,i) (f ? bf2f(((const unsigned short*)(p))[i]) : ((const float*)(p))[i])
    if (t < 256){
        binf[t] = CV(bin,t);
        a1sf[t] = CV(a1s,t); a1df[t] = CV(a1d,t);
        a2sf[t] = CV(a2s,t); a2df[t] = CV(a2d,t);
    }
    if (t < OD) bof[t] = CV(bo,t);
    #undef CV
}

// ---- W[K][N] -> WT[NP][K] bf16 (flag-aware read), zero-pad rows N..NP ------
__global__ void k_transpose(const void* __restrict__ B, unsigned short* __restrict__ BT,
                            int K, int N, int NP, const int* __restrict__ flag){
    __shared__ float tile[32][33];
    int k0 = blockIdx.x * 32, n0 = blockIdx.y * 32;
    int tx = threadIdx.x, ty = threadIdx.y;   // 32 x 8
    int f = *flag;
    #pragma unroll
    for (int i = 0; i < 4; i++){
        int k = k0 + ty + i*8, n = n0 + tx;
        float v = 0.f;
        if (n < N){
            v = f ? bf2f(((const unsigned short*)B)[(size_t)k*N + n])
                  : ((const float*)B)[(size_t)k*N + n];
        }
        tile[ty + i*8][tx] = v;
    }
    __syncthreads();
    #pragma unroll
    for (int i = 0; i < 4; i++){
        int n = n0 + ty + i*8, k = k0 + tx;
        if (n < NP) BT[(size_t)n*K + k] = f2bf(tile[tx][ty + i*8]);
    }
}

// ---- CSR build -------------------------------------------------------------
__global__ void k_hist(const int* __restrict__ dst, int* __restrict__ deg){
    int e = blockIdx.x*blockDim.x + threadIdx.x;
    if (e < NE) atomicAdd(&deg[dst[e]], 1);
}

__global__ void k_scan(const int* __restrict__ deg, int* __restrict__ rowptr, int* __restrict__ cnt){
    __shared__ int sums[1024];
    int t = threadIdx.x;
    int base = t * 10;
    int local[10];
    int s = 0;
    #pragma unroll
    for (int i = 0; i < 10; i++){
        int idx = base + i;
        int v = (idx < NN) ? deg[idx] : 0;
        local[i] = s; s += v;
    }
    sums[t] = s;
    __syncthreads();
    for (int off = 1; off < 1024; off <<= 1){
        int v = (t >= off) ? sums[t - off] : 0;
        __syncthreads();
        sums[t] += v;
        __syncthreads();
    }
    int excl = sums[t] - s;
    #pragma unroll
    for (int i = 0; i < 10; i++){
        int idx = base + i;
        if (idx < NN){ int v = excl + local[i]; rowptr[idx] = v; cnt[idx] = v; }
    }
    if (t == 1023) rowptr[NN] = sums[1023];
}

__global__ void k_fill(const int* __restrict__ src, const int* __restrict__ dst,
                       int* __restrict__ cnt, int* __restrict__ col){
    int e = blockIdx.x*blockDim.x + threadIdx.x;
    if (e < NE){
        int p = atomicAdd(&cnt[dst[e]], 1);
        col[p] = src[e];
    }
}

// ---- bf16 MFMA GEMM: C[M,N] = A[M,K] @ BT[N,K]^T (+bias) -------------------
// BM=64, BK=64, 256 threads = 4 waves in 2x2; wave tile 32 x (BN/2).
template<int BN, int FP32OUT>
__global__ __launch_bounds__(256)
void k_mfma(const unsigned short* __restrict__ A, const unsigned short* __restrict__ BT,
            const float* __restrict__ bias, void* __restrict__ C,
            int M, int N, int K){
    constexpr int BM = 64, BK = 64, LDR = BK + 8;   // 72-elem rows: 2-way banks only
    constexpr int MI = 2;
    constexpr int NJ = BN / 32;                      // 128->4, 64->2
    __shared__ unsigned short As[BM * LDR];
    __shared__ unsigned short Bs[BN * LDR];
    int t = threadIdx.x;
    int lane = t & 63, wid = t >> 6;
    int wr = wid >> 1, wc = wid & 1;
    int rowBase = blockIdx.x * BM, colBase = blockIdx.y * BN;

    f32x4 acc[MI][NJ] = {};

    int arow = rowBase + (t >> 2); if (arow >= M) arow = M - 1;
    const unsigned short* Ag = A + (size_t)arow * K + (t & 3) * 16;
    int brow, bcoff;
    if (BN == 128){ brow = t >> 1; bcoff = (t & 1) * 32; }
    else          { brow = t >> 2; bcoff = (t & 3) * 16; }
    const unsigned short* Bg = BT + (size_t)(colBase + brow) * K + bcoff;
    unsigned short* Asw = &As[(t >> 2) * LDR + (t & 3) * 16];
    unsigned short* Bsw = &Bs[brow * LDR + bcoff];

    for (int k0 = 0; k0 < K; k0 += BK){
        *(bf16x8*)(Asw)     = *(const bf16x8*)(Ag + k0);
        *(bf16x8*)(Asw + 8) = *(const bf16x8*)(Ag + k0 + 8);
        if (BN == 128){
            #pragma unroll
            for (int c = 0; c < 4; c++)
                *(bf16x8*)(Bsw + c*8) = *(const bf16x8*)(Bg + k0 + c*8);
        } else {
            *(bf16x8*)(Bsw)     = *(const bf16x8*)(Bg + k0);
            *(bf16x8*)(Bsw + 8) = *(const bf16x8*)(Bg + k0 + 8);
        }
        __syncthreads();
        #pragma unroll
        for (int ks = 0; ks < 2; ks++){
            bf16x8 a[MI], b[NJ];
            #pragma unroll
            for (int mi = 0; mi < MI; mi++)
                a[mi] = *(const bf16x8*)&As[(wr*32 + mi*16 + (lane & 15)) * LDR + ks*32 + (lane >> 4)*8];
            #pragma unroll
            for (int nj = 0; nj < NJ; nj++)
                b[nj] = *(const bf16x8*)&Bs[(wc*(BN/2) + nj*16 + (lane & 15)) * LDR + ks*32 + (lane >> 4)*8];
            #pragma unroll
            for (int mi = 0; mi < MI; mi++)
                #pragma unroll
                for (int nj = 0; nj < NJ; nj++)
                    acc[mi][nj] = __builtin_amdgcn_mfma_f32_16x16x32_bf16(a[mi], b[nj], acc[mi][nj], 0, 0, 0);
        }
        __syncthreads();
    }
    #pragma unroll
    for (int mi = 0; mi < MI; mi++){
        #pragma unroll
        for (int nj = 0; nj < NJ; nj++){
            int col = colBase + wc*(BN/2) + nj*16 + (lane & 15);
            #pragma unroll
            for (int r = 0; r < 4; r++){
                int row = rowBase + wr*32 + mi*16 + (lane >> 4)*4 + r;
                if (row < M && col < N){
                    float v = acc[mi][nj][r] + (bias ? bias[col] : 0.f);
                    if (FP32OUT) ((float*)C)[(size_t)row * N + col] = v;
                    else         ((unsigned short*)C)[(size_t)row * N + col] = f2bf(v);
                }
            }
        }
    }
}

// ---- attention logits (Wh bf16): one wave per node -------------------------
__global__ __launch_bounds__(256)
void k_alpha(const unsigned short* __restrict__ Wh, const float* __restrict__ asrc,
             const float* __restrict__ adst, float* __restrict__ als, float* __restrict__ ald){
    int node = blockIdx.x * 4 + (threadIdx.x >> 6);
    int lane = threadIdx.x & 63;
    if (node >= NN) return;
    ushort4 wv = *(const ushort4*)&Wh[(size_t)node * HD + (lane << 2)];
    float w0 = bf2f(wv.x), w1 = bf2f(wv.y), w2 = bf2f(wv.z), w3 = bf2f(wv.w);
    float4 s4 = *(const float4*)&asrc[lane << 2];
    float4 d4 = *(const float4*)&adst[lane << 2];
    float ps = w0*s4.x + w1*s4.y + w2*s4.z + w3*s4.w;
    float pd = w0*d4.x + w1*d4.y + w2*d4.z + w3*d4.w;
    ps += __shfl_xor(ps, 1); pd += __shfl_xor(pd, 1);
    ps += __shfl_xor(ps, 2); pd += __shfl_xor(pd, 2);
    ps += __shfl_xor(ps, 4); pd += __shfl_xor(pd, 4);
    if ((lane & 7) == 0){
        als[node * NH + (lane >> 3)] = ps;
        ald[node * NH + (lane >> 3)] = pd;
    }
}

// ---- per-destination softmax + aggregation (Wh bf16 in, out bf16) ----------
__global__ __launch_bounds__(64)
void k_agg(const int* __restrict__ rowptr, const int* __restrict__ col,
           const unsigned short* __restrict__ Wh, const float* __restrict__ als,
           const float* __restrict__ ald, unsigned short* __restrict__ out){
    __shared__ float pshm[64][NH];
    __shared__ int scol[64];
    int node = blockIdx.x;
    int lane = threadIdx.x;
    int b = rowptr[node], e = rowptr[node + 1];
    int hL = lane >> 3;
    float ad[NH];
    #pragma unroll
    for (int h = 0; h < NH; h++) ad[h] = ald[node * NH + h];
    float m[NH], den[NH];
    #pragma unroll
    for (int h = 0; h < NH; h++){ m[h] = -INFINITY; den[h] = 0.f; }
    float4 acc = make_float4(0.f, 0.f, 0.f, 0.f);

    for (int cb = b; cb < e; cb += 64){
        int ne_ = min(64, e - cb);
        float ev[NH];
        if (lane < ne_){
            int s = col[cb + lane];
            scol[lane] = s;
            const float* ap = &als[(size_t)s * NH];
            #pragma unroll
            for (int h = 0; h < NH; h++){
                float v = ap[h] + ad[h];
                ev[h] = v > 0.f ? v : NEG * v;
            }
        } else {
            #pragma unroll
            for (int h = 0; h < NH; h++) ev[h] = -INFINITY;
        }
        float cm[NH];
        #pragma unroll
        for (int h = 0; h < NH; h++) cm[h] = ev[h];
        #pragma unroll
        for (int off = 1; off < 64; off <<= 1){
            #pragma unroll
            for (int h = 0; h < NH; h++) cm[h] = fmaxf(cm[h], __shfl_xor(cm[h], off));
        }
        float r[NH];
        #pragma unroll
        for (int h = 0; h < NH; h++){
            float nm = fmaxf(m[h], cm[h]);
            r[h] = __expf(m[h] - nm);
            den[h] *= r[h];
            m[h] = nm;
        }
        float rr = r[hL];
        acc.x *= rr; acc.y *= rr; acc.z *= rr; acc.w *= rr;
        float dp[NH];
        if (lane < ne_){
            #pragma unroll
            for (int h = 0; h < NH; h++){
                float p = __expf(ev[h] - m[h]);
                pshm[lane][h] = p;
                dp[h] = p;
            }
        } else {
            #pragma unroll
            for (int h = 0; h < NH; h++) dp[h] = 0.f;
        }
        #pragma unroll
        for (int off = 1; off < 64; off <<= 1){
            #pragma unroll
            for (int h = 0; h < NH; h++) dp[h] += __shfl_xor(dp[h], off);
        }
        #pragma unroll
        for (int h = 0; h < NH; h++) den[h] += dp[h];
        __syncthreads();
        for (int j = 0; j < ne_; j++){
            int s = scol[j];
            float p = pshm[j][hL];
            ushort4 wv = *(const ushort4*)&Wh[(size_t)s * HD + (lane << 2)];
            acc.x += p * bf2f(wv.x); acc.y += p * bf2f(wv.y);
            acc.z += p * bf2f(wv.z); acc.w += p * bf2f(wv.w);
        }
        __syncthreads();
    }
    float inv = 1.f / fmaxf(den[hL], 1e-9f);
    ushort4 o;
    o.x = f2bf(fmaxf(acc.x * inv, 0.f));
    o.y = f2bf(fmaxf(acc.y * inv, 0.f));
    o.z = f2bf(fmaxf(acc.z * inv, 0.f));
    o.w = f2bf(fmaxf(acc.w * inv, 0.f));
    *(ushort4*)&out[(size_t)node * HD + (lane << 2)] = o;
}

// ---- fp32 scratch -> d_out (flag dtype) ------------------------------------
__global__ void store_any(const float* __restrict__ in, void* __restrict__ out, int n,
                          const int* __restrict__ flag){
    int i = blockIdx.x*blockDim.x + threadIdx.x;
    if (i >= n) return;
    if (*flag) ((__hip_bfloat16*)out)[i] = __float2bfloat16(in[i]);
    else       ((float*)out)[i] = in[i];
}

extern "C" void kernel_launch(void* const* d_in, const int* in_sizes, int n_in,
                              void* d_out, int out_size, void* d_ws, size_t ws_size,
                              hipStream_t stream){
    const void* x_p   = d_in[0];
    const int*  eidx  = (const int*)d_in[1];
    const void* Win_p = d_in[2];
    const void* bin_p = d_in[3];
    const void* W1_p  = d_in[4];
    const void* a1s_p = d_in[5];
    const void* a1d_p = d_in[6];
    const void* W2_p  = d_in[7];
    const void* a2s_p = d_in[8];
    const void* a2d_p = d_in[9];
    const void* Wo_p  = d_in[10];
    const void* bo_p  = d_in[11];

    char* base = (char*)d_ws;
    size_t off = 0;
    auto alloc = [&](size_t bytes){ void* p = base + off; off = (off + bytes + 255) & ~255ULL; return p; };

    unsigned short* xb   = (unsigned short*)alloc((size_t)NN * IND * 2);
    unsigned short* WinT = (unsigned short*)alloc((size_t)HD * IND * 2);   // [256][512]
    unsigned short* W1T  = (unsigned short*)alloc((size_t)HD * HD * 2);    // [256][256]
    unsigned short* W2T  = (unsigned short*)alloc((size_t)HD * HD * 2);
    unsigned short* WoT  = (unsigned short*)alloc((size_t)64 * HD * 2);    // [64][256], rows 40..63 zero
    float* binf = (float*)alloc(HD * 4);
    float* a1sf = (float*)alloc(HD * 4);
    float* a1df = (float*)alloc(HD * 4);
    float* a2sf = (float*)alloc(HD * 4);
    float* a2df = (float*)alloc(HD * 4);
    float* bof  = (float*)alloc(64 * 4);
    unsigned short* h1b = (unsigned short*)alloc((size_t)NN * HD * 2);     // reused as h3b
    unsigned short* Whb = (unsigned short*)alloc((size_t)NN * HD * 2);
    unsigned short* h2b = (unsigned short*)alloc((size_t)NN * HD * 2);
    float* als  = (float*)alloc((size_t)NN * NH * 4);
    float* ald  = (float*)alloc((size_t)NN * NH * 4);
    float* outf = (float*)alloc((size_t)NN * OD * 4);
    int* col    = (int*)alloc((size_t)NE * 4);
    int* rowptr = (int*)alloc((NN + 1) * 4);
    int* cnt    = (int*)alloc(NN * 4);
    int* deg    = (int*)alloc(NN * 4);
    int* dflag  = (int*)alloc(16);
    unsigned short* h3b = h1b;

    const int* src = eidx;
    const int* dst = eidx + NE;

    auto cdiv = [](int a, int b){ return (a + b - 1) / b; };

    k_detect<<<1,64,0,stream>>>((const unsigned short*)Win_p, dflag);

    // prep inputs
    k_prep_x<<<cdiv(NN*IND/8,256),256,0,stream>>>(x_p, xb, NN*IND/8, dflag);
    k_cvt_small<<<1,256,0,stream>>>(bin_p, a1s_p, a1d_p, a2s_p, a2d_p, bo_p,
                                    binf, a1sf, a1df, a2sf, a2df, bof, dflag);
    k_transpose<<<dim3(IND/32, HD/32), dim3(32,8),0,stream>>>(Win_p, WinT, IND, HD, HD, dflag);
    k_transpose<<<dim3(HD/32,  HD/32), dim3(32,8),0,stream>>>(W1_p,  W1T,  HD,  HD, HD, dflag);
    k_transpose<<<dim3(HD/32,  HD/32), dim3(32,8),0,stream>>>(W2_p,  W2T,  HD,  HD, HD, dflag);
    k_transpose<<<dim3(HD/32,  64/32), dim3(32,8),0,stream>>>(Wo_p,  WoT,  HD,  OD, 64, dflag);

    // CSR by destination
    k_zero_i<<<cdiv(NN,256),256,0,stream>>>(deg, NN);
    k_hist<<<cdiv(NE,256),256,0,stream>>>(dst, deg);
    k_scan<<<1,1024,0,stream>>>(deg, rowptr, cnt);
    k_fill<<<cdiv(NE,256),256,0,stream>>>(src, dst, cnt, col);

    dim3 g256(cdiv(NN,64), HD/128);   // (157, 2)

    // input linear: h1 = x @ W_in + b_in
    k_mfma<128,0><<<g256,256,0,stream>>>(xb, WinT, binf, h1b, NN, HD, IND);

    // GAT layer 1
    k_mfma<128,0><<<g256,256,0,stream>>>(h1b, W1T, nullptr, Whb, NN, HD, HD);
    k_alpha<<<cdiv(NN,4),256,0,stream>>>(Whb, a1sf, a1df, als, ald);
    k_agg<<<NN,64,0,stream>>>(rowptr, col, Whb, als, ald, h2b);

    // GAT layer 2
    k_mfma<128,0><<<g256,256,0,stream>>>(h2b, W2T, nullptr, Whb, NN, HD, HD);
    k_alpha<<<cdiv(NN,4),256,0,stream>>>(Whb, a2sf, a2df, als, ald);
    k_agg<<<NN,64,0,stream>>>(rowptr, col, Whb, als, ald, h3b);

    // output head: out = h3 @ W_out + b_out
    k_mfma<64,1><<<dim3(cdiv(NN,64),1),256,0,stream>>>(h3b, WoT, bof, outf, NN, OD, HD);
    store_any<<<cdiv(NN*OD,256),256,0,stream>>>(outf, d_out, NN*OD, dflag);
}